// Round 1
// baseline (2276.638 us; speedup 1.0000x reference)
//
#include <hip/hip_runtime.h>
#include <math.h>

#define Hn   256
#define En   128
#define Vn   256
#define TPn  32
#define BTn  2048
#define NSV  8              // seqs per WG
#define NWG  (BTn / NSV)    // 256 workgroups
#define NT   1024           // 16 waves
#define HROW 272            // padded LDS row stride (floats) for h
#define SROW 260            // padded LDS row stride for score stage

// physical index within an h row: +4 float skew per 64-chunk (conflict-free quads)
__device__ __forceinline__ int hp(int k) { return k + 4 * (k >> 6); }

__device__ __forceinline__ float sigf(float x) {
    return __builtin_amdgcn_rcpf(1.0f + __expf(-x));
}
__device__ __forceinline__ float tanh_fast(float x) {
    float e = __expf(2.0f * x);
    return 1.0f - 2.0f * __builtin_amdgcn_rcpf(e + 1.0f);
}
// barrier that waits LDS only (lgkmcnt) -- global prefetch stays in flight
__device__ __forceinline__ void bar_lgkm() {
    asm volatile("s_waitcnt lgkmcnt(0)" ::: "memory");
    __builtin_amdgcn_s_barrier();
    asm volatile("" ::: "memory");
}

__device__ __forceinline__ unsigned long long amax_key(float sc, int v) {
    unsigned fb = __float_as_uint(sc);
    fb = (fb & 0x80000000u) ? ~fb : (fb | 0x80000000u);   // order-preserving
    return ((unsigned long long)fb << 32) | (unsigned)(Vn - 1 - v);  // first-idx tie
}
__device__ __forceinline__ float dot4(float4 a, float4 b, float acc) {
    return fmaf(a.x, b.x, fmaf(a.y, b.y, fmaf(a.z, b.z, fmaf(a.w, b.w, acc))));
}

// Butterfly reduce-scatter over the 4 K-chunk lanes (ch = lane&3).
__device__ __forceinline__ void rs8(const float v[8], int ch, float& a, float& b) {
    const bool hi2 = (ch & 2) != 0;
    float w0, w1, w2, w3;
    { float s = hi2 ? v[0] : v[4]; float r = __shfl_xor(s, 2, 64); w0 = (hi2 ? v[4] : v[0]) + r; }
    { float s = hi2 ? v[1] : v[5]; float r = __shfl_xor(s, 2, 64); w1 = (hi2 ? v[5] : v[1]) + r; }
    { float s = hi2 ? v[2] : v[6]; float r = __shfl_xor(s, 2, 64); w2 = (hi2 ? v[6] : v[2]) + r; }
    { float s = hi2 ? v[3] : v[7]; float r = __shfl_xor(s, 2, 64); w3 = (hi2 ? v[7] : v[3]) + r; }
    const bool hi1 = (ch & 1) != 0;
    { float s = hi1 ? w0 : w2; float r = __shfl_xor(s, 1, 64); a = (hi1 ? w2 : w0) + r; }
    { float s = hi1 ? w1 : w3; float r = __shfl_xor(s, 1, 64); b = (hi1 ? w3 : w1) + r; }
}

// ---------------- staged-load / compute macros (static reg tiles) ----------------
#define ELOAD(W, j) do { \
        W[0] = Wr[((j) * 4 + 0) * NT + tid]; \
        W[1] = Wr[((j) * 4 + 1) * NT + tid]; \
        W[2] = Wr[((j) * 4 + 2) * NT + tid]; \
        W[3] = Wr[((j) * 4 + 3) * NT + tid]; \
    } while (0)
#define ESTEP(W, j) do { \
        _Pragma("unroll") \
        for (int s = 0; s < 8; ++s) { \
            float4 hv = *(const float4*)&hb[s * HROW + 4 * (j)]; \
            ag[0][s] = dot4(W[0], hv, ag[0][s]); \
            ag[1][s] = dot4(W[1], hv, ag[1][s]); \
            ag[2][s] = dot4(W[2], hv, ag[2][s]); \
            ag[3][s] = dot4(W[3], hv, ag[3][s]); \
        } \
    } while (0)
#define DLOADW(W, F, j) do { \
        W[0] = Wr[((j) * 4 + 0) * NT + tid]; \
        W[1] = Wr[((j) * 4 + 1) * NT + tid]; \
        W[2] = Wr[((j) * 4 + 2) * NT + tid]; \
        W[3] = Wr[((j) * 4 + 3) * NT + tid]; \
        F    = Fr[(j) * NT + tid]; \
    } while (0)
#define DLOADF(F, j) do { F = Fr[(j) * NT + tid]; } while (0)
#define DSTEP(W, F, j) do { \
        _Pragma("unroll") \
        for (int s = 0; s < 8; ++s) { \
            float4 hv = *(const float4*)&hb[s * HROW + 4 * (j)]; \
            ag[0][s] = dot4(W[0], hv, ag[0][s]); \
            ag[1][s] = dot4(W[1], hv, ag[1][s]); \
            ag[2][s] = dot4(W[2], hv, ag[2][s]); \
            ag[3][s] = dot4(W[3], hv, ag[3][s]); \
            af[s]    = dot4(F,  hv, af[s]); \
        } \
    } while (0)
#define FSTEP(F, j) do { \
        _Pragma("unroll") \
        for (int s = 0; s < 8; ++s) { \
            float4 hv = *(const float4*)&hb[s * HROW + 4 * (j)]; \
            af[s] = dot4(F, hv, af[s]); \
        } \
    } while (0)

// ---------------- precompute kernels ----------------

__global__ void make_ptab(float4* __restrict__ Pp, const float* __restrict__ emb,
                          const float* __restrict__ Wih, const float* __restrict__ bih,
                          const float* __restrict__ bhh) {
    int v = blockIdx.x, u = threadIdx.x;
    __shared__ __align__(16) float es[En];
    if (u < En) es[u] = emb[v * En + u];
    __syncthreads();
    float a[4];
#pragma unroll
    for (int g = 0; g < 4; ++g) {
        int r = g * Hn + u;
        float acc = bih[r] + bhh[r];
        const float4* w4 = (const float4*)(Wih + r * En);
        const float4* e4 = (const float4*)es;
        for (int k = 0; k < En / 4; ++k) acc = dot4(w4[k], e4[k], acc);
        a[g] = acc;
    }
    Pp[v * Hn + u] = make_float4(a[0], a[1], a[2], a[3]);
}

__global__ void pack_wr(float4* __restrict__ Wr, const float* __restrict__ W) {
    int idx = blockIdx.x * 256 + threadIdx.x;
    int l = idx & 1023, stripe = idx >> 10;     // stripe 0..63
    int j4 = stripe >> 2, g = stripe & 3;
    int u = l >> 2, ch = l & 3;
    const float* s = W + (g * Hn + u) * Hn + ch * 64 + 4 * j4;
    Wr[idx] = make_float4(s[0], s[1], s[2], s[3]);
}

__global__ void pack_fr(float4* __restrict__ Fr, const float* __restrict__ W) {
    int idx = blockIdx.x * 256 + threadIdx.x;
    int l = idx & 1023, j4 = idx >> 10;
    int u = l >> 2, ch = l & 3;
    const float* s = W + u * Hn + ch * 64 + 4 * j4;
    Fr[idx] = make_float4(s[0], s[1], s[2], s[3]);
}

// ---------------- encoder ----------------
__global__ __launch_bounds__(NT, 4) void enc_kernel(
    const float4* __restrict__ Wr, const float4* __restrict__ Ptu,
    const int* __restrict__ phon, const int* __restrict__ lens,
    float* __restrict__ h0dec) {
    const int tid = threadIdx.x, wg = blockIdx.x;
    const int u = tid >> 2, ch = tid & 3;
    const int sA = 2 * ch, sB = 2 * ch + 1;
    __shared__ __align__(16) float hs[NSV * HROW];
    __shared__ int lsh[NSV];

    for (int i = tid; i < NSV * HROW; i += NT) hs[i] = 0.0f;
    if (tid < NSV) lsh[tid] = lens[wg * NSV + tid];

    float4 wsA[4], wsB[4];
    ELOAD(wsA, 0);                      // prefetch first tile; survives barrier
    float cA = 0.f, cB = 0.f;
    bar_lgkm();
    int mx = 0;
#pragma unroll
    for (int i = 0; i < NSV; ++i) mx = max(mx, lsh[i]);
    const int lenA = lsh[sA], lenB = lsh[sB];

    for (int t = 0; t < mx; ++t) {
        const int tokA = phon[(wg * NSV + sA) * TPn + t];
        const int tokB = phon[(wg * NSV + sB) * TPn + t];
        const float4 pA = Ptu[tokA * Hn + u];      // hidden by K-loop
        const float4 pB = Ptu[tokB * Hn + u];
        float ag[4][8];
#pragma unroll
        for (int g = 0; g < 4; ++g)
#pragma unroll
            for (int s = 0; s < 8; ++s) ag[g][s] = 0.0f;
        const float* hb = hs + ch * 68;
#pragma unroll 2
        for (int jp = 0; jp < 8; ++jp) {
            const int j0 = 2 * jp, j1 = 2 * jp + 1;
            ELOAD(wsB, j1);                 // issue j1 while computing j0
            ESTEP(wsA, j0);
            ELOAD(wsA, (j1 + 1) & 15);      // j0+2; at jp==7 this prefetches next t's j=0
            ESTEP(wsB, j1);
        }
        float gA[4], gB[4];
#pragma unroll
        for (int g = 0; g < 4; ++g) rs8(ag[g], ch, gA[g], gB[g]);
        bar_lgkm();   // all K-reads of hs done (lgkm only; weight prefetch stays in flight)
        float hA, hB;
        {
            float gi = sigf(gA[0] + pA.x), gf = sigf(gA[1] + pA.y);
            float gg = tanh_fast(gA[2] + pA.z), go = sigf(gA[3] + pA.w);
            cA = fmaf(gf, cA, gi * gg); hA = go * tanh_fast(cA);
        }
        {
            float gi = sigf(gB[0] + pB.x), gf = sigf(gB[1] + pB.y);
            float gg = tanh_fast(gB[2] + pB.z), go = sigf(gB[3] + pB.w);
            cB = fmaf(gf, cB, gi * gg); hB = go * tanh_fast(cB);
        }
        const int pu = hp(u);
        hs[sA * HROW + pu] = hA;
        hs[sB * HROW + pu] = hB;
        if (t == lenA - 1) h0dec[(wg * NSV + sA) * Hn + u] = hA;
        if (t == lenB - 1) h0dec[(wg * NSV + sB) * Hn + u] = hB;
        bar_lgkm();   // new h visible
    }
}

// ---------------- decoder ----------------
// Iteration i: fc(h_i) -> scores_{i-1} -> argmax -> tok_i; gates(h_i,tok_i) -> h_{i+1}.
__global__ __launch_bounds__(NT, 4) void dec_kernel(
    const float4* __restrict__ Wr, const float4* __restrict__ Fr,
    const float4* __restrict__ Ptu, const float* __restrict__ fcb,
    const float* __restrict__ h0dec, const int* __restrict__ sosp,
    float* __restrict__ out) {
    const int tid = threadIdx.x, wg = blockIdx.x;
    const int u = tid >> 2, ch = tid & 3;
    const int sA = 2 * ch, sB = 2 * ch + 1;
    const int wv = tid >> 6, ln = tid & 63;
    __shared__ __align__(16) float hs[NSV * HROW];
    __shared__ __align__(16) float scx[NSV * SROW];
    __shared__ unsigned long long kex[16][NSV];
    __shared__ int toks[NSV];

    {   // stage h0
        int s = tid >> 7, k = (tid & 127) * 2;
        float2 v = *(const float2*)&h0dec[(wg * NSV + s) * Hn + k];
        int pk = hp(k);
        hs[s * HROW + pk] = v.x;
        hs[s * HROW + pk + 1] = v.y;
    }
    if (tid < NSV) toks[tid] = sosp[0];
    const float fb = fcb[u];

    float4 wsA[4], wsB[4], fsA, fsB;
    DLOADW(wsA, fsA, 0);                // prefetch first tile; survives barrier
    float cA = 0.f, cB = 0.f;
    bar_lgkm();

    for (int i = 0; i <= TPn; ++i) {
        const bool full = (i < TPn);
        float ag[4][8], af[8];
#pragma unroll
        for (int g = 0; g < 4; ++g)
#pragma unroll
            for (int s = 0; s < 8; ++s) ag[g][s] = 0.0f;
#pragma unroll
        for (int s = 0; s < 8; ++s) af[s] = 0.0f;
        const float* hb = hs + ch * 68;
        if (full) {
#pragma unroll 2
            for (int jp = 0; jp < 8; ++jp) {
                const int j0 = 2 * jp, j1 = 2 * jp + 1;
                DLOADW(wsB, fsB, j1);
                DSTEP(wsA, fsA, j0);
                DLOADW(wsA, fsA, (j1 + 1) & 15);   // jp==7: prefetch next iter's j=0
                DSTEP(wsB, fsB, j1);
            }
        } else {   // last iteration: fc only (fsA holds j=0 from previous iter's wrap)
#pragma unroll 2
            for (int jp = 0; jp < 8; ++jp) {
                const int j0 = 2 * jp, j1 = 2 * jp + 1;
                DLOADF(fsB, j1);
                FSTEP(fsA, j0);
                DLOADF(fsA, (j1 + 1) & 15);
                FSTEP(fsB, j1);
            }
        }
        float gA[4], gB[4], fA, fB;
#pragma unroll
        for (int g = 0; g < 4; ++g) rs8(ag[g], ch, gA[g], gB[g]);
        rs8(af, ch, fA, fB);

        if (i > 0) {   // scores_{i-1} for v=u, seqs sA,sB
            float scA = fA + fb, scB = fB + fb;
            scx[sA * SROW + u] = scA;
            scx[sB * SROW + u] = scB;
            unsigned long long kA = amax_key(scA, u);
            unsigned long long kB = amax_key(scB, u);
#pragma unroll
            for (int off = 4; off < 64; off <<= 1) {
                unsigned long long oA = __shfl_xor(kA, off, 64);
                unsigned long long oB = __shfl_xor(kB, off, 64);
                if (oA > kA) kA = oA;
                if (oB > kB) kB = oB;
            }
            if (ln < 4) {          // ln==ch here
                kex[wv][sA] = kA;
                kex[wv][sB] = kB;
            }
        }
        bar_lgkm();   // hs reads done; scx/kex published

        if (i > 0) {
            if (tid < NSV) {       // global argmax per seq
                unsigned long long k = kex[0][tid];
#pragma unroll
                for (int w = 1; w < 16; ++w)
                    if (kex[w][tid] > k) k = kex[w][tid];
                toks[tid] = (Vn - 1) - (int)(k & 0xffffffffu);
            }
            {   // coalesced out store of scores_{i-1}
                int s = tid >> 7, k = (tid & 127) * 2;
                float2 v = *(const float2*)&scx[s * SROW + k];
                *(float2*)&out[((long)(wg * NSV + s) * TPn + (i - 1)) * Vn + k] = v;
            }
        }
        bar_lgkm();   // toks visible

        if (full) {
            const int tokA = toks[sA], tokB = toks[sB];
            const float4 pA = Ptu[tokA * Hn + u];
            const float4 pB = Ptu[tokB * Hn + u];
            float hA, hB;
            {
                float gi = sigf(gA[0] + pA.x), gf = sigf(gA[1] + pA.y);
                float gg = tanh_fast(gA[2] + pA.z), go = sigf(gA[3] + pA.w);
                cA = fmaf(gf, cA, gi * gg); hA = go * tanh_fast(cA);
            }
            {
                float gi = sigf(gB[0] + pB.x), gf = sigf(gB[1] + pB.y);
                float gg = tanh_fast(gB[2] + pB.z), go = sigf(gB[3] + pB.w);
                cB = fmaf(gf, cB, gi * gg); hB = go * tanh_fast(cB);
            }
            const int pu = hp(u);
            hs[sA * HROW + pu] = hA;
            hs[sB * HROW + pu] = hB;
        }
        bar_lgkm();   // new h visible
    }
}

// ---------------- launch ----------------
extern "C" void kernel_launch(void* const* d_in, const int* in_sizes, int n_in,
                              void* d_out, int out_size, void* d_ws, size_t ws_size,
                              hipStream_t stream) {
    const int*   phon = (const int*)d_in[0];
    const int*   lens = (const int*)d_in[1];
    const float* emb  = (const float*)d_in[2];
    const float* eWih = (const float*)d_in[3];
    const float* eWhh = (const float*)d_in[4];
    const float* ebih = (const float*)d_in[5];
    const float* ebhh = (const float*)d_in[6];
    const float* dWih = (const float*)d_in[7];
    const float* dWhh = (const float*)d_in[8];
    const float* dbih = (const float*)d_in[9];
    const float* dbhh = (const float*)d_in[10];
    const float* fcW  = (const float*)d_in[11];
    const float* fcb  = (const float*)d_in[12];
    const int*   sos  = (const int*)d_in[13];
    float* out = (float*)d_out;

    float4* Ptu_e = (float4*)d_ws;           // 65536 f4 = 1 MB
    float4* Ptu_d = Ptu_e + 65536;           // 1 MB
    float4* Wr_e  = Ptu_d + 65536;           // 1 MB
    float4* Wr_d  = Wr_e + 65536;            // 1 MB
    float4* Fr    = Wr_d + 65536;            // 256 KB
    float*  h0d   = (float*)(Fr + 16384);    // 2 MB

    make_ptab<<<256, 256, 0, stream>>>(Ptu_e, emb, eWih, ebih, ebhh);
    make_ptab<<<256, 256, 0, stream>>>(Ptu_d, emb, dWih, dbih, dbhh);
    pack_wr<<<256, 256, 0, stream>>>(Wr_e, eWhh);
    pack_wr<<<256, 256, 0, stream>>>(Wr_d, dWhh);
    pack_fr<<<64, 256, 0, stream>>>(Fr, fcW);
    enc_kernel<<<NWG, NT, 0, stream>>>(Wr_e, Ptu_e, phon, lens, h0d);
    dec_kernel<<<NWG, NT, 0, stream>>>(Wr_d, Fr, Ptu_d, fcb, h0d, sos, out);
}